// Round 2
// baseline (70.003 us; speedup 1.0000x reference)
//
#include <hip/hip_runtime.h>
#include <hip/hip_bf16.h>
#include <stdint.h>

// GraphAttentionLayer: B=8, S=2048, F=128, H=4, D=32
// proj: Wh[b,h,s,d] = feat[b,s,:] . W[h,:,d]   (bf16 MFMA)
// attn: out[b,s,h*32+d] = softmax_t(mask(Wh_q . Wh_t / sqrt(D))) @ Wh
//   fixed-max softmax (max=0): scores are small; softmax is shift-invariant;
//   masked entries contribute exactly 0 like the NEG_INF reference.

namespace {
constexpr int S = 2048;
constexpr int F = 128;
constexpr int H = 4;
constexpr int D = 32;

typedef __attribute__((ext_vector_type(4))) float f32x4;
typedef __attribute__((ext_vector_type(8))) short s16x8;
typedef __attribute__((ext_vector_type(4))) short s16x4;

__device__ __forceinline__ short f2bf(float f) {
  __hip_bfloat16 h = __float2bfloat16(f);
  short s; __builtin_memcpy(&s, &h, sizeof(s)); return s;
}
__device__ __forceinline__ float bf2f(short s) {
  __hip_bfloat16 h; __builtin_memcpy(&h, &s, sizeof(s));
  return __bfloat162float(h);
}

// async global->LDS, 16B per lane; dest = wave-uniform base + lane*16
__device__ __forceinline__ void gll16(const void* g, void* l) {
  __builtin_amdgcn_global_load_lds(
      (const __attribute__((address_space(1))) uint32_t*)(uintptr_t)g,
      (__attribute__((address_space(3))) uint32_t*)(uint32_t)(uintptr_t)l,
      16, 0, 0);
}

__global__ __launch_bounds__(256) void gat_proj(const float* __restrict__ feat,
                                                const float* __restrict__ W,
                                                short* __restrict__ Wh) {
  __shared__ __align__(16) short ftile[64][136];  // 64 rows x 128 f (pad 8)
  const int tid = threadIdx.x;
  const int w = tid >> 6;            // wave = head
  const int l = tid & 63;
  const int ln = l & 15, lg = l >> 4;
  const int row0 = blockIdx.x * 64;  // flat row in [B*S]

#pragma unroll
  for (int i = 0; i < 4; ++i) {
    int c = i * 256 + tid;           // 8-float chunk
    int r = c >> 4, c8 = (c & 15) * 8;
    const float* src = feat + (size_t)(row0 + r) * F + c8;
    float4 v0 = *(const float4*)src;
    float4 v1 = *(const float4*)(src + 4);
    s16x8 v;
    v[0]=f2bf(v0.x); v[1]=f2bf(v0.y); v[2]=f2bf(v0.z); v[3]=f2bf(v0.w);
    v[4]=f2bf(v1.x); v[5]=f2bf(v1.y); v[6]=f2bf(v1.z); v[7]=f2bf(v1.w);
    *(s16x8*)&ftile[r][c8] = v;
  }

  // W fragments: B[k][n], n = nt*16+ln, k = ks*32+lg*8+j
  s16x8 bfr[4][2];
#pragma unroll
  for (int ks = 0; ks < 4; ++ks)
#pragma unroll
    for (int nt = 0; nt < 2; ++nt) {
      s16x8 v;
#pragma unroll
      for (int j = 0; j < 8; ++j)
        v[j] = f2bf(W[((size_t)w * F + ks*32 + lg*8 + j) * D + nt*16 + ln]);
      bfr[ks][nt] = v;
    }
  __syncthreads();

  const f32x4 z4 = {0.f, 0.f, 0.f, 0.f};
#pragma unroll
  for (int mt = 0; mt < 4; ++mt) {
    s16x8 a[4];
#pragma unroll
    for (int ks = 0; ks < 4; ++ks)
      a[ks] = *(const s16x8*)&ftile[mt*16 + ln][ks*32 + lg*8];
#pragma unroll
    for (int nt = 0; nt < 2; ++nt) {
      f32x4 c = z4;
#pragma unroll
      for (int ks = 0; ks < 4; ++ks)
        c = __builtin_amdgcn_mfma_f32_16x16x32_bf16(a[ks], bfr[ks][nt], c, 0, 0, 0);
#pragma unroll
      for (int r = 0; r < 4; ++r) {
        int srow = row0 + mt*16 + lg*4 + r;
        int b = srow >> 11, s = srow & (S - 1);
        Wh[(((size_t)b * H + w) * S + s) * D + nt*16 + ln] = f2bf(c[r]);
      }
    }
  }
}

__global__ __launch_bounds__(256, 2) void gat_attn(const int* __restrict__ adj,
                                                   const short* __restrict__ Wh,
                                                   float* __restrict__ out) {
  // LDS 65536 B total -> 2 blocks/CU
  __shared__ __align__(16) int   adjm[2][32][64];      // raw adj, 16B-granule XOR swizzled
  __shared__ __align__(16) short vtt[H][2][32][64];    // V^T [d][t], granule-swizzled, dbuf
  __shared__ __align__(16) short ptl[H][32][64];       // P [q][t], granule-swizzled

  const int tid = threadIdx.x;
  const int w = tid >> 6;            // wave = head
  const int l = tid & 63;
  const int ln = l & 15, lg = l >> 4, g4 = (l >> 4) * 4;
  const int e3 = ln & 7;
  const int b = blockIdx.x >> 6;
  const int s0 = (blockIdx.x & 63) * 32;

  const short* WhBH = Wh + ((size_t)b * H + w) * S * D;
  const int* adjB = adj + (size_t)b * S * S;
  short* pw = &ptl[w][0][0];

  // Q fragments (B-operand of swapped QK^T), prescaled by log2(e)/sqrt(D)
  const float cs = 0.25503486f;
  s16x8 qf[2];
#pragma unroll
  for (int qt = 0; qt < 2; ++qt) {
    s16x8 v = *(const s16x8*)&WhBH[(size_t)(s0 + qt*16 + ln) * D + lg*8];
    s16x8 o;
#pragma unroll
    for (int j = 0; j < 8; ++j) o[j] = f2bf(bf2f(v[j]) * cs);
    qf[qt] = o;
  }

  const f32x4 z4 = {0.f, 0.f, 0.f, 0.f};
  f32x4 accO[2][2];
#pragma unroll
  for (int i = 0; i < 2; ++i)
#pragma unroll
    for (int j = 0; j < 2; ++j) accO[i][j] = z4;
  float psum[2] = {0.f, 0.f};

  // ---- prologue: adj tile 0 (async), K frags tile 0, V^T tile 0
#pragma unroll
  for (int i = 0; i < 2; ++i) {
    int r = w*8 + i*4 + (l >> 4);
    const int* src = adjB + (size_t)(s0 + r) * S + ((ln ^ (r & 7)) << 2);
    gll16(src, (char*)&adjm[0][0][0] + w*2048 + i*1024);
  }
  s16x8 kf[4];
#pragma unroll
  for (int mt = 0; mt < 4; ++mt)
    kf[mt] = *(const s16x8*)&WhBH[(size_t)(mt*16 + ln) * D + lg*8];
  {
    short* vb = &vtt[w][0][0][0];
#pragma unroll
    for (int mt = 0; mt < 4; ++mt) {
      int tg = mt*2 + (ln >> 3);
#pragma unroll
      for (int j = 0; j < 8; ++j) {
        int d = lg*8 + j;
        vb[d*64 + ((tg ^ ((j + lg) & 7)) << 3) + e3] = kf[mt][j];
      }
    }
  }
  __syncthreads();

  int cur = 0;
#pragma unroll 1
  for (int it = 0; it < S / 64; ++it) {
    const int nxt = cur ^ 1;
    const int t0n = (it + 1) * 64;
    const bool pf = (it < S / 64 - 1);

    // 1. async adj stage for next tile
    if (pf) {
#pragma unroll
      for (int i = 0; i < 2; ++i) {
        int r = w*8 + i*4 + (l >> 4);
        const int* src = adjB + (size_t)(s0 + r) * S + t0n + ((ln ^ (r & 7)) << 2);
        gll16(src, (char*)&adjm[nxt][0][0] + w*2048 + i*1024);
      }
    }
    // 2. K frags for next tile (registers)
    s16x8 kn[4];
    if (pf) {
#pragma unroll
      for (int mt = 0; mt < 4; ++mt)
        kn[mt] = *(const s16x8*)&WhBH[(size_t)(t0n + mt*16 + ln) * D + lg*8];
    }

    // 3. swapped QK^T: rows = t (m), cols = q (n)
    f32x4 accS[4][2];
#pragma unroll
    for (int mt = 0; mt < 4; ++mt)
#pragma unroll
      for (int qt = 0; qt < 2; ++qt)
        accS[mt][qt] = __builtin_amdgcn_mfma_f32_16x16x32_bf16(kf[mt], qf[qt], z4, 0, 0, 0);

    // 4. softmax (fixed max=0): p = adj ? exp2(s') : 0; rowsum; P -> LDS
#pragma unroll
    for (int mt = 0; mt < 4; ++mt) {
#pragma unroll
      for (int qt = 0; qt < 2; ++qt) {
        const int4 a = *(const int4*)&adjm[cur][qt*16 + ln][((mt*4 + lg) ^ e3) << 2];
        f32x4 sv = accS[mt][qt];
        float p0 = a.x ? __builtin_amdgcn_exp2f(sv[0]) : 0.f;
        float p1 = a.y ? __builtin_amdgcn_exp2f(sv[1]) : 0.f;
        float p2 = a.z ? __builtin_amdgcn_exp2f(sv[2]) : 0.f;
        float p3 = a.w ? __builtin_amdgcn_exp2f(sv[3]) : 0.f;
        psum[qt] += (p0 + p1) + (p2 + p3);
        s16x4 pk;
        pk[0] = f2bf(p0); pk[1] = f2bf(p1); pk[2] = f2bf(p2); pk[3] = f2bf(p3);
        int pg = mt*2 + (lg >> 1);
        *(s16x4*)&pw[(qt*16 + ln)*64 + ((pg ^ e3) << 3) + (lg & 1)*4] = pk;
      }
    }

    // 5. PV operand reads (same-wave LDS, in-order after the P writes)
    s16x8 ap[2][2];
#pragma unroll
    for (int qt = 0; qt < 2; ++qt)
#pragma unroll
      for (int kt = 0; kt < 2; ++kt)
        ap[qt][kt] = *(const s16x8*)&pw[(qt*16 + ln)*64 + (((kt*4 + lg) ^ e3) << 3)];

    const short* vr = &vtt[w][cur][0][0];
    s16x8 bv[2][2];
#pragma unroll
    for (int kt = 0; kt < 2; ++kt)
#pragma unroll
      for (int nt = 0; nt < 2; ++nt) {
        int dp = nt*16 + ln;
        int f = (ln + (ln >> 3) + 2*nt) & 7;
        bv[kt][nt] = *(const s16x8*)&vr[dp*64 + (((kt*4 + lg) ^ f) << 3)];
      }

    // 6. PV MFMA
#pragma unroll
    for (int qt = 0; qt < 2; ++qt)
#pragma unroll
      for (int nt = 0; nt < 2; ++nt)
#pragma unroll
        for (int kt = 0; kt < 2; ++kt)
          accO[qt][nt] = __builtin_amdgcn_mfma_f32_16x16x32_bf16(
              ap[qt][kt], bv[kt][nt], accO[qt][nt], 0, 0, 0);

    // 7. scatter next V^T from kn; roll K frags
    if (pf) {
      short* vb = &vtt[w][nxt][0][0];
#pragma unroll
      for (int mt = 0; mt < 4; ++mt) {
        int tg = mt*2 + (ln >> 3);
#pragma unroll
        for (int j = 0; j < 8; ++j) {
          int d = lg*8 + j;
          vb[d*64 + ((tg ^ ((j + lg) & 7)) << 3) + e3] = kn[mt][j];
        }
        kf[mt] = kn[mt];
      }
    }
    __syncthreads();
    cur = nxt;
  }

  // ---- epilogue: rowsum across the 4 lg lane-copies, normalize, store
#pragma unroll
  for (int qt = 0; qt < 2; ++qt) {
    psum[qt] += __shfl_xor(psum[qt], 16, 64);
    psum[qt] += __shfl_xor(psum[qt], 32, 64);
  }
#pragma unroll
  for (int qt = 0; qt < 2; ++qt)
#pragma unroll
    for (int r = 0; r < 4; ++r) {
      float rs = __shfl(psum[qt], g4 + r, 16);  // rowsum for q-local = g4+r
      float inv = 1.0f / rs;
#pragma unroll
      for (int nt = 0; nt < 2; ++nt)
        out[((size_t)b * S + s0 + qt*16 + g4 + r) * (H * D) + w*32 + nt*16 + ln]
            = accO[qt][nt][r] * inv;
    }
}

}  // namespace

extern "C" void kernel_launch(void* const* d_in, const int* in_sizes, int n_in,
                              void* d_out, int out_size, void* d_ws, size_t ws_size,
                              hipStream_t stream) {
  const float* feat = (const float*)d_in[0];   // [8,2048,128] f32
  const int* adj    = (const int*)d_in[1];     // [8,2048,2048] i32
  const float* W    = (const float*)d_in[2];   // [4,128,32] f32
  float* out        = (float*)d_out;           // [8,2048,128] f32
  short* Wh         = (short*)d_ws;            // [8,4,2048,32] bf16 = 4 MiB scratch

  gat_proj<<<(8 * S) / 64, 256, 0, stream>>>(feat, W, Wh);
  gat_attn<<<8 * (S / 32), 256, 0, stream>>>(adj, Wh, out);
}

// Round 3
// 68.937 us; speedup vs baseline: 1.0155x; 1.0155x over previous
//
#include <hip/hip_runtime.h>
#include <hip/hip_bf16.h>
#include <stdint.h>

// GraphAttentionLayer: B=8, S=2048, F=128, H=4, D=32
// proj: Wh[b,h,s,d] (row-major) AND WhT[b,h,d,s] (transposed) via bf16 MFMA
// attn: out[b,s,h*32+d] = softmax_t(mask(Wh_q . Wh_t / sqrt(D))) @ Wh
//   fixed-max softmax (max=0, scores bounded), swapped QK^T and swapped PV.

namespace {
constexpr int S = 2048;
constexpr int F = 128;
constexpr int H = 4;
constexpr int D = 32;

typedef __attribute__((ext_vector_type(4))) float f32x4;
typedef __attribute__((ext_vector_type(8))) short s16x8;
typedef __attribute__((ext_vector_type(4))) short s16x4;

__device__ __forceinline__ short f2bf(float f) {
  __hip_bfloat16 h = __float2bfloat16(f);
  short s; __builtin_memcpy(&s, &h, sizeof(s)); return s;
}
__device__ __forceinline__ float bf2f(short s) {
  __hip_bfloat16 h; __builtin_memcpy(&h, &s, sizeof(s));
  return __bfloat162float(h);
}

__global__ __launch_bounds__(256) void gat_proj(const float* __restrict__ feat,
                                                const float* __restrict__ W,
                                                short* __restrict__ Wh,
                                                short* __restrict__ WhT) {
  __shared__ __align__(16) short ftile[64][136];  // 64 rows x 128 f (pad 8)
  const int tid = threadIdx.x;
  const int w = tid >> 6;            // wave = head
  const int l = tid & 63;
  const int ln = l & 15, lg = l >> 4, g4 = (l >> 4) * 4;
  const int row0 = blockIdx.x * 64;  // flat row in [B*S]
  const int b = row0 >> 11;
  const int sl0 = row0 & (S - 1);

#pragma unroll
  for (int i = 0; i < 4; ++i) {
    int c = i * 256 + tid;           // 8-float chunk
    int r = c >> 4, c8 = (c & 15) * 8;
    const float* src = feat + (size_t)(row0 + r) * F + c8;
    float4 v0 = *(const float4*)src;
    float4 v1 = *(const float4*)(src + 4);
    s16x8 v;
    v[0]=f2bf(v0.x); v[1]=f2bf(v0.y); v[2]=f2bf(v0.z); v[3]=f2bf(v0.w);
    v[4]=f2bf(v1.x); v[5]=f2bf(v1.y); v[6]=f2bf(v1.z); v[7]=f2bf(v1.w);
    *(s16x8*)&ftile[r][c8] = v;
  }

  // W fragments: B[k][n], n = nt*16+ln, k = ks*32+lg*8+j
  s16x8 bfr[4][2];
#pragma unroll
  for (int ks = 0; ks < 4; ++ks)
#pragma unroll
    for (int nt = 0; nt < 2; ++nt) {
      s16x8 v;
#pragma unroll
      for (int j = 0; j < 8; ++j)
        v[j] = f2bf(W[((size_t)w * F + ks*32 + lg*8 + j) * D + nt*16 + ln]);
      bfr[ks][nt] = v;
    }
  __syncthreads();

  const f32x4 z4 = {0.f, 0.f, 0.f, 0.f};
#pragma unroll
  for (int mt = 0; mt < 4; ++mt) {
    s16x8 a[4];
#pragma unroll
    for (int ks = 0; ks < 4; ++ks)
      a[ks] = *(const s16x8*)&ftile[mt*16 + ln][ks*32 + lg*8];
#pragma unroll
    for (int nt = 0; nt < 2; ++nt) {
      f32x4 c = z4;
#pragma unroll
      for (int ks = 0; ks < 4; ++ks)
        c = __builtin_amdgcn_mfma_f32_16x16x32_bf16(a[ks], bfr[ks][nt], c, 0, 0, 0);
      // D[m][n]: s-row = row0 + mt*16 + g4 + r, d-col = nt*16 + ln
      s16x4 tv;
#pragma unroll
      for (int r = 0; r < 4; ++r) {
        tv[r] = f2bf(c[r]);
        int srow = row0 + mt*16 + g4 + r;
        int s = srow & (S - 1);
        Wh[(((size_t)b * H + w) * S + s) * D + nt*16 + ln] = tv[r];
      }
      // transposed: 4 consecutive s at fixed d -> one 8B store
      *(s16x4*)&WhT[(((size_t)b * H + w) * D + nt*16 + ln) * S + sl0 + mt*16 + g4] = tv;
    }
  }
}

__global__ __launch_bounds__(256, 2) void gat_attn(const int* __restrict__ adj,
                                                   const short* __restrict__ Wh,
                                                   const short* __restrict__ WhT,
                                                   float* __restrict__ out) {
  // LDS: adj byte-mask (pad-20 dword rows) + P tiles = 5120 + 16384 B
  __shared__ unsigned adjw[2][32][20];
  __shared__ __align__(16) short ptl[H][32][64];   // P [q][t], granule-swizzled

  const int tid = threadIdx.x;
  const int w = tid >> 6;            // wave = head
  const int l = tid & 63;
  const int ln = l & 15, lg = l >> 4, g4 = (l >> 4) * 4;
  const int e3 = ln & 7;
  const int b = blockIdx.x >> 6;
  const int s0 = (blockIdx.x & 63) * 32;

  const short* WhBH = Wh + ((size_t)b * H + w) * S * D;
  const short* WhTBH = WhT + ((size_t)b * H + w) * D * S;
  const int* adjB = adj + (size_t)b * S * S;
  short* pw = &ptl[w][0][0];

  // adj staging assignment: thread -> rows (ra, 16+ra), 4-int col group cg
  const int ra = tid >> 4;           // 0..15
  const int cg = tid & 15;
  const int* adjR0 = adjB + (size_t)(s0 + ra) * S + cg * 4;
  const int* adjR1 = adjB + (size_t)(s0 + 16 + ra) * S + cg * 4;

  // Q fragments (B-operand of swapped QK^T), prescaled by log2(e)/sqrt(D)
  const float cs = 0.25503486f;
  s16x8 qf[2];
#pragma unroll
  for (int qt = 0; qt < 2; ++qt) {
    s16x8 v = *(const s16x8*)&WhBH[(size_t)(s0 + qt*16 + ln) * D + lg*8];
    s16x8 o;
#pragma unroll
    for (int j = 0; j < 8; ++j) o[j] = f2bf(bf2f(v[j]) * cs);
    qf[qt] = o;
  }

  const f32x4 z4 = {0.f, 0.f, 0.f, 0.f};
  f32x4 accO[2][2];                  // [dt][qt] of O^T
#pragma unroll
  for (int i = 0; i < 2; ++i)
#pragma unroll
    for (int j = 0; j < 2; ++j) accO[i][j] = z4;
  float psum[2] = {0.f, 0.f};

  // ---- prologue: tile 0 ----
  int4 a0 = *(const int4*)adjR0;
  int4 a1 = *(const int4*)adjR1;
  s16x8 kf[4];
#pragma unroll
  for (int mt = 0; mt < 4; ++mt)
    kf[mt] = *(const s16x8*)&WhBH[(size_t)(mt*16 + ln) * D + lg*8];
  s16x8 av[2][2];                    // V^T A-frags: [dt][kt]
#pragma unroll
  for (int dt = 0; dt < 2; ++dt)
#pragma unroll
    for (int kt = 0; kt < 2; ++kt)
      av[dt][kt] = *(const s16x8*)&WhTBH[(size_t)(dt*16 + ln) * S + kt*32 + lg*8];
  adjw[0][ra][cg]      = (unsigned)a0.x | ((unsigned)a0.y << 8) |
                         ((unsigned)a0.z << 16) | ((unsigned)a0.w << 24);
  adjw[0][16 + ra][cg] = (unsigned)a1.x | ((unsigned)a1.y << 8) |
                         ((unsigned)a1.z << 16) | ((unsigned)a1.w << 24);
  __syncthreads();

#pragma unroll 1
  for (int it = 0; it < S / 64; ++it) {
    const int cur = it & 1, nxt = cur ^ 1;
    const int t0n = (it + 1) * 64;
    const bool pf = (it < S / 64 - 1);

    // issue next-tile loads early (T14 split)
    int4 a0n, a1n;
    s16x8 kn[4], avn[2][2];
    if (pf) {
      a0n = *(const int4*)(adjR0 + t0n);
      a1n = *(const int4*)(adjR1 + t0n);
#pragma unroll
      for (int mt = 0; mt < 4; ++mt)
        kn[mt] = *(const s16x8*)&WhBH[(size_t)(t0n + mt*16 + ln) * D + lg*8];
#pragma unroll
      for (int dt = 0; dt < 2; ++dt)
#pragma unroll
        for (int kt = 0; kt < 2; ++kt)
          avn[dt][kt] = *(const s16x8*)&WhTBH[(size_t)(dt*16 + ln) * S + t0n + kt*32 + lg*8];
    }

    // swapped QK^T: rows = t (m), cols = q (n)
    f32x4 accS[4][2];
#pragma unroll
    for (int mt = 0; mt < 4; ++mt)
#pragma unroll
      for (int qt = 0; qt < 2; ++qt)
        accS[mt][qt] = __builtin_amdgcn_mfma_f32_16x16x32_bf16(kf[mt], qf[qt], z4, 0, 0, 0);

    // softmax (fixed max=0): p = adjbyte ? exp2(s') : 0; rowsum; P -> LDS
#pragma unroll
    for (int qt = 0; qt < 2; ++qt) {
      const unsigned* ab = &adjw[cur][qt*16 + ln][lg];
#pragma unroll
      for (int mt = 0; mt < 4; ++mt) {
        unsigned m = ab[mt*4];
        f32x4 sv = accS[mt][qt];
        float p0 = (m & 0xffu)       ? __builtin_amdgcn_exp2f(sv[0]) : 0.f;
        float p1 = (m & 0xff00u)     ? __builtin_amdgcn_exp2f(sv[1]) : 0.f;
        float p2 = (m & 0xff0000u)   ? __builtin_amdgcn_exp2f(sv[2]) : 0.f;
        float p3 = (m & 0xff000000u) ? __builtin_amdgcn_exp2f(sv[3]) : 0.f;
        psum[qt] += (p0 + p1) + (p2 + p3);
        s16x4 pk;
        pk[0] = f2bf(p0); pk[1] = f2bf(p1); pk[2] = f2bf(p2); pk[3] = f2bf(p3);
        int pg = mt*2 + (lg >> 1);
        *(s16x4*)&pw[(qt*16 + ln)*64 + ((pg ^ e3) << 3) + (lg & 1)*4] = pk;
      }
    }

    // P fragments (same-wave LDS, in-order after writes)
    s16x8 ap[2][2];
#pragma unroll
    for (int qt = 0; qt < 2; ++qt)
#pragma unroll
      for (int kt = 0; kt < 2; ++kt)
        ap[qt][kt] = *(const s16x8*)&pw[(qt*16 + ln)*64 + (((kt*4 + lg) ^ e3) << 3)];

    // swapped PV: O^T[d][q] += V^T[d][t] * P[q][t]
#pragma unroll
    for (int dt = 0; dt < 2; ++dt)
#pragma unroll
      for (int qt = 0; qt < 2; ++qt)
#pragma unroll
        for (int kt = 0; kt < 2; ++kt)
          accO[dt][qt] = __builtin_amdgcn_mfma_f32_16x16x32_bf16(
              av[dt][kt], ap[qt][kt], accO[dt][qt], 0, 0, 0);

    // commit next adj tile; roll K/V frags
    if (pf) {
      adjw[nxt][ra][cg]      = (unsigned)a0n.x | ((unsigned)a0n.y << 8) |
                               ((unsigned)a0n.z << 16) | ((unsigned)a0n.w << 24);
      adjw[nxt][16 + ra][cg] = (unsigned)a1n.x | ((unsigned)a1n.y << 8) |
                               ((unsigned)a1n.z << 16) | ((unsigned)a1n.w << 24);
#pragma unroll
      for (int mt = 0; mt < 4; ++mt) kf[mt] = kn[mt];
#pragma unroll
      for (int dt = 0; dt < 2; ++dt)
#pragma unroll
        for (int kt = 0; kt < 2; ++kt) av[dt][kt] = avn[dt][kt];
    }
    __syncthreads();
  }

  // ---- epilogue: reduce rowsums across lg copies, normalize, f32x4 stores
#pragma unroll
  for (int qt = 0; qt < 2; ++qt) {
    psum[qt] += __shfl_xor(psum[qt], 16, 64);
    psum[qt] += __shfl_xor(psum[qt], 32, 64);
  }
#pragma unroll
  for (int qt = 0; qt < 2; ++qt) {
    float inv = 1.0f / psum[qt];     // q = qt*16 + ln is per-lane
#pragma unroll
    for (int dt = 0; dt < 2; ++dt) {
      f32x4 o;
#pragma unroll
      for (int r = 0; r < 4; ++r) o[r] = accO[dt][qt][r] * inv;
      *(f32x4*)&out[((size_t)b * S + s0 + qt*16 + ln) * (H * D) + w*32 + dt*16 + g4] = o;
    }
  }
}

}  // namespace

extern "C" void kernel_launch(void* const* d_in, const int* in_sizes, int n_in,
                              void* d_out, int out_size, void* d_ws, size_t ws_size,
                              hipStream_t stream) {
  const float* feat = (const float*)d_in[0];   // [8,2048,128] f32
  const int* adj    = (const int*)d_in[1];     // [8,2048,2048] i32
  const float* W    = (const float*)d_in[2];   // [4,128,32] f32
  float* out        = (float*)d_out;           // [8,2048,128] f32
  short* Wh         = (short*)d_ws;            // [8,4,2048,32] bf16 = 4 MiB
  short* WhT        = (short*)d_ws + (size_t)8 * H * S * D;  // [8,4,32,2048] bf16 = 4 MiB

  gat_proj<<<(8 * S) / 64, 256, 0, stream>>>(feat, W, Wh, WhT);
  gat_attn<<<8 * (S / 32), 256, 0, stream>>>(adj, Wh, WhT, out);
}